// Round 7
// baseline (21582.860 us; speedup 1.0000x reference)
//
#include <hip/hip_runtime.h>
#include <hip/hip_bf16.h>

typedef __attribute__((ext_vector_type(8))) short short8;
typedef __attribute__((ext_vector_type(4))) float f32x4;
typedef __attribute__((ext_vector_type(2))) unsigned long long u64x2;

#define MFMA16(a, b, c) __builtin_amdgcn_mfma_f32_16x16x32_bf16((a), (b), (c), 0, 0, 0)

#define B_ 64
#define T_ 512

// ws layout (bytes)
#define FLG_OFF  0u          // 4 groups * 16 u32 = 256B (one 64B line per group)
#define HNEW_OFF 1024u       // 4 groups * 16 rows * 512 * 2B = 65536
#define CAT_OFF  66560u      // 512*64*1024*2 = 67108864
#define W0F_OFF  67175424u   // 262144*2 = 524288   (W0h blob, K=512)
#define W1F_OFF  67699712u   // 524288              (W1 blob, K=512)
#define WAF_OFF  68224000u   // 524288*2 = 1048576  (Wout[:, :512] blob, K=1024)
#define WBT_OFF  69272576u   // 2097152             (Wout[:, 512:] transposed)
#define EPR_OFF  71369728u   // 1024*512*4 = 2097152 (E' = emb @ W0[:512,:], fp32)
// end: 73466880

__device__ __forceinline__ short f2bf(float f) {
  unsigned u = __float_as_uint(f);
  unsigned r = (u + 0x7fffu + ((u >> 16) & 1u)) >> 16;
  return (short)r;
}

// agent-scope coherent 16B load (LLC; proven R1-R6)
__device__ __forceinline__ short8 ld8(const short* p) {
  union { u64x2 q; short8 s; } u;
  u.q.x = __hip_atomic_load((const unsigned long long*)p, __ATOMIC_RELAXED, __HIP_MEMORY_SCOPE_AGENT);
  u.q.y = __hip_atomic_load(((const unsigned long long*)p) + 1, __ATOMIC_RELAXED, __HIP_MEMORY_SCOPE_AGENT);
  return u.s;
}

// ---------------------------------------------------------------------------
// Weight packing: bf16 MFMA B-fragment blobs.
// Blob for (K,N): idx = ((cb*(K/32) + s)*64 + l)*8 + j
//   holds W[s*32 + (l>>4)*8 + j][cb*16 + (l&15)]
// W0f: W0h = W0[512:1024, :] (K=512). W1f: W1 (K=512). Waf: Wout[:, :512]
// (K=1024). WbT[v][k] = Wout[k][512+v] for the logits GEMM.
// ---------------------------------------------------------------------------
__global__ void pack_weights(const float* __restrict__ W0, const float* __restrict__ W1,
                             const float* __restrict__ Wout,
                             short* __restrict__ W0f, short* __restrict__ W1f,
                             short* __restrict__ Waf, short* __restrict__ WbT) {
  const int total = 262144 + 262144 + 524288 + 1048576;
  for (int i = blockIdx.x * blockDim.x + threadIdx.x; i < total; i += gridDim.x * blockDim.x) {
    if (i < 262144) {                       // W0h: K=512, N=512
      int j = i & 7, l = (i >> 3) & 63, rest = i >> 9;
      int s = rest & 15, cb = rest >> 4;
      int k = s * 32 + ((l >> 4) << 3) + j, n = (cb << 4) + (l & 15);
      W0f[i] = f2bf(W0[(512 + k) * 512 + n]);
    } else if (i < 524288) {                // W1: K=512, N=512
      int ii = i - 262144;
      int j = ii & 7, l = (ii >> 3) & 63, rest = ii >> 9;
      int s = rest & 15, cb = rest >> 4;
      int k = s * 32 + ((l >> 4) << 3) + j, n = (cb << 4) + (l & 15);
      W1f[ii] = f2bf(W1[k * 512 + n]);
    } else if (i < 1048576) {               // Wa: Wout[:, :512], K=1024
      int ii = i - 524288;
      int j = ii & 7, l = (ii >> 3) & 63, rest = ii >> 9;
      int s = rest & 31, cb = rest >> 5;
      int k = s * 32 + ((l >> 4) << 3) + j, n = (cb << 4) + (l & 15);
      Waf[ii] = f2bf(Wout[k * 1536 + n]);
    } else {                                // WbT
      int ii = i - 1048576;
      int v = ii >> 10, kk = ii & 1023;
      WbT[ii] = f2bf(Wout[kk * 1536 + 512 + v]);
    }
  }
}

// ---------------------------------------------------------------------------
// E'[v][n] = sum_k emb[v][k] * W0[k][n]  (fp32 exact; k,n < 512, v < 1024)
// 64 blocks x 256 threads, 16 vocab rows per block, emb tile in LDS.
// ---------------------------------------------------------------------------
__global__ __launch_bounds__(256) void eprime(const float* __restrict__ emb,
                                              const float* __restrict__ W0,
                                              float* __restrict__ Epr) {
  __shared__ float eL[16][512];
  const int v0 = blockIdx.x * 16, tid = threadIdx.x;
  for (int i = tid; i < 16 * 512; i += 256)
    eL[i >> 9][i & 511] = emb[(v0 + (i >> 9)) * 512 + (i & 511)];
  __syncthreads();
  float acc[32];
#pragma unroll
  for (int v = 0; v < 32; ++v) acc[v] = 0.f;
#pragma unroll 4
  for (int k = 0; k < 512; ++k) {
    float wa = W0[k * 512 + tid];
    float wb = W0[k * 512 + 256 + tid];
#pragma unroll
    for (int v = 0; v < 16; ++v) {
      float e = eL[v][k];
      acc[2 * v]     = fmaf(e, wa, acc[2 * v]);
      acc[2 * v + 1] = fmaf(e, wb, acc[2 * v + 1]);
    }
  }
#pragma unroll
  for (int v = 0; v < 16; ++v) {
    Epr[(v0 + v) * 512 + tid]       = acc[2 * v];
    Epr[(v0 + v) * 512 + 256 + tid] = acc[2 * v + 1];
  }
}

// ---------------------------------------------------------------------------
// Recurrence: 16 blocks x 1024 threads. Block (g = bid>>2, m = bid&3):
// g owns batch rows [16g, 16g+16); every block computes h0 and h1 for its
// rows REDUNDANTLY (W0h + W1 fully register-resident), and h_new only for
// its 128-col slice (Wa column-split by m). ONE inter-block barrier per step
// (4-member, R2-proven agent-scope flags). All cross-block data via
// agent-scope atomics (LLC). Intra-block exchange via swizzled LDS.
// ---------------------------------------------------------------------------
__global__ __launch_bounds__(1024, 1) void rnn_recur(
    const int* __restrict__ x,
    const float* __restrict__ b0, const float* __restrict__ b1, const float* __restrict__ bout,
    const short* __restrict__ W0f, const short* __restrict__ W1f, const short* __restrict__ Waf,
    const float* __restrict__ Epr,
    short* __restrict__ cat, unsigned* __restrict__ hnewG, unsigned* __restrict__ flags) {
  const int g = blockIdx.x >> 2, m = blockIdx.x & 3;
  const int tid = threadIdx.x, l = tid & 63, w = tid >> 6;
  const int ks = w >> 3, cs = w & 7;       // phase-1/2 roles: K-half, 64-col slice
  const int kq = w >> 2, cw = w & 3;       // phase-3 roles: K-quarter, 32-col slice
  const int q = l >> 4, r16 = l & 15;

  __shared__ short hst[16 * 512];          // h stage (swizzled)
  __shared__ short h0s[16 * 512];          // h0 (swizzled)
  __shared__ short h1s[16 * 512];          // h1 (swizzled)
  __shared__ float part[8][4][16][17];     // ph1/2 partials [cs][cb][r][c+pad]
  __shared__ float part3[3][4][2][16][17]; // ph3 partials [kq][cw][cb][r][c+pad]
  __shared__ short pub[16 * 128];          // h_new slice staging

  // ---- register-resident weight fragments
  short8 w0r[4][8], w1r[4][8], war[2][8];
#pragma unroll
  for (int cb = 0; cb < 4; ++cb) {
    int cbg = cs * 4 + cb;
#pragma unroll
    for (int si = 0; si < 8; ++si) {
      int s = ks * 8 + si;
      w0r[cb][si] = *(const short8*)&W0f[((cbg * 16 + s) * 64 + l) * 8];
      w1r[cb][si] = *(const short8*)&W1f[((cbg * 16 + s) * 64 + l) * 8];
    }
  }
#pragma unroll
  for (int cb = 0; cb < 2; ++cb) {
    int cbg = m * 8 + cw * 2 + cb;
#pragma unroll
    for (int si = 0; si < 8; ++si) {
      int s = kq * 8 + si;
      war[cb][si] = *(const short8*)&Waf[((cbg * 32 + s) * 64 + l) * 8];
    }
  }

  float b0v[4], b1v[4];
#pragma unroll
  for (int cb = 0; cb < 4; ++cb) {
    int c = (cs * 4 + cb) * 16 + r16;
    b0v[cb] = b0[c]; b1v[cb] = b1[c];
  }
  float bov[2];
#pragma unroll
  for (int cb = 0; cb < 2; ++cb) bov[cb] = bout[(m * 8 + cw * 2 + cb) * 16 + r16];

  // ---- E' prefetch (finisher ks==1 waves hold 16 values for their acc cells)
  float epf[16];
  if (ks == 1) {
#pragma unroll
    for (int j = 0; j < 4; ++j) {
      int xi = x[(g * 16 + q * 4 + j) * T_ + 0];
#pragma unroll
      for (int cb = 0; cb < 4; ++cb)
        epf[cb * 4 + j] = Epr[xi * 512 + (cs * 4 + cb) * 16 + r16];
    }
  }

  for (int t = 0; t < T_; ++t) {
    // ===== barrier: h_new(t-1) published by all 4 members =====
    if (tid < 4) {
      int spins = 0;
      while (__hip_atomic_load(&flags[g * 16 + tid], __ATOMIC_RELAXED,
                               __HIP_MEMORY_SCOPE_AGENT) < (unsigned)t) {
        if (++spins > (1 << 22)) break;   // stopgap: degrade, don't hang
      }
    }
    __syncthreads();
    // ===== cooperative stage: h (16KB) -> swizzled LDS =====
    {
      short8 hv = ld8((const short*)hnewG + g * 8192 + tid * 8);
      int rr = tid >> 6, cbyte = (tid & 63) * 16;
      *(short8*)&hst[rr * 512 + ((cbyte ^ ((rr & 7) << 6)) >> 1)] = hv;
    }
    __syncthreads();

    // ===== phase 1: h0 = relu(E'[x_t] + h @ W0h + b0) =====
    {
      f32x4 acc[4];
#pragma unroll
      for (int cb = 0; cb < 4; ++cb) acc[cb] = (f32x4){0.f, 0.f, 0.f, 0.f};
#pragma unroll
      for (int si = 0; si < 8; ++si) {
        int kbyte = (ks * 256 + si * 32 + q * 8) * 2;
        short8 af = *(const short8*)&hst[r16 * 512 + ((kbyte ^ ((r16 & 7) << 6)) >> 1)];
#pragma unroll
        for (int cb = 0; cb < 4; ++cb) acc[cb] = MFMA16(af, w0r[cb][si], acc[cb]);
      }
      if (ks == 0) {
#pragma unroll
        for (int cb = 0; cb < 4; ++cb)
#pragma unroll
          for (int j = 0; j < 4; ++j) part[cs][cb][q * 4 + j][r16] = acc[cb][j];
      }
      __syncthreads();
      if (ks == 1) {
#pragma unroll
        for (int cb = 0; cb < 4; ++cb) {
          int c = (cs * 4 + cb) * 16 + r16;
#pragma unroll
          for (int j = 0; j < 4; ++j) {
            int rr = q * 4 + j;
            float v = acc[cb][j] + part[cs][cb][rr][r16] + epf[cb * 4 + j] + b0v[cb];
            short bf = f2bf(fmaxf(v, 0.f));
            h0s[rr * 512 + (((c * 2) ^ ((rr & 7) << 6)) >> 1)] = bf;
            if (m == 0) cat[(t * B_ + g * 16 + rr) * 1024 + c] = bf;
          }
        }
      }
      __syncthreads();
    }

    // ===== phase 2: h1 = relu(h0 @ W1 + b1) =====
    {
      f32x4 acc[4];
#pragma unroll
      for (int cb = 0; cb < 4; ++cb) acc[cb] = (f32x4){0.f, 0.f, 0.f, 0.f};
#pragma unroll
      for (int si = 0; si < 8; ++si) {
        int kbyte = (ks * 256 + si * 32 + q * 8) * 2;
        short8 af = *(const short8*)&h0s[r16 * 512 + ((kbyte ^ ((r16 & 7) << 6)) >> 1)];
#pragma unroll
        for (int cb = 0; cb < 4; ++cb) acc[cb] = MFMA16(af, w1r[cb][si], acc[cb]);
      }
      if (ks == 0) {
#pragma unroll
        for (int cb = 0; cb < 4; ++cb)
#pragma unroll
          for (int j = 0; j < 4; ++j) part[cs][cb][q * 4 + j][r16] = acc[cb][j];
      }
      __syncthreads();
      if (ks == 1) {
#pragma unroll
        for (int cb = 0; cb < 4; ++cb) {
          int c = (cs * 4 + cb) * 16 + r16;
#pragma unroll
          for (int j = 0; j < 4; ++j) {
            int rr = q * 4 + j;
            float v = acc[cb][j] + part[cs][cb][rr][r16] + b1v[cb];
            short bf = f2bf(fmaxf(v, 0.f));
            h1s[rr * 512 + (((c * 2) ^ ((rr & 7) << 6)) >> 1)] = bf;
            if (m == 1) cat[(t * B_ + g * 16 + rr) * 1024 + 512 + c] = bf;
          }
        }
        // E' prefetch for t+1 (overlaps phase 3)
        if (t + 1 < T_) {
#pragma unroll
          for (int j = 0; j < 4; ++j) {
            int xi = x[(g * 16 + q * 4 + j) * T_ + t + 1];
#pragma unroll
            for (int cb = 0; cb < 4; ++cb)
              epf[cb * 4 + j] = Epr[xi * 512 + (cs * 4 + cb) * 16 + r16];
          }
        }
      }
      __syncthreads();
    }

    if (t == T_ - 1) break;               // last h_new unused; cat complete

    // ===== phase 3: h_new slice = relu([h0,h1] @ Wa[:, m-slice] + bout) =====
    {
      f32x4 a3[2];
#pragma unroll
      for (int cb = 0; cb < 2; ++cb) a3[cb] = (f32x4){0.f, 0.f, 0.f, 0.f};
      const short* src = (kq < 2) ? h0s : h1s;
      int kb = (kq & 1) * 256;
#pragma unroll
      for (int si = 0; si < 8; ++si) {
        int kbyte = (kb + si * 32 + q * 8) * 2;
        short8 af = *(const short8*)&src[r16 * 512 + ((kbyte ^ ((r16 & 7) << 6)) >> 1)];
#pragma unroll
        for (int cb = 0; cb < 2; ++cb) a3[cb] = MFMA16(af, war[cb][si], a3[cb]);
      }
      if (kq < 3) {
#pragma unroll
        for (int cb = 0; cb < 2; ++cb)
#pragma unroll
          for (int j = 0; j < 4; ++j) part3[kq][cw][cb][q * 4 + j][r16] = a3[cb][j];
      }
      __syncthreads();
      if (kq == 3) {
#pragma unroll
        for (int cb = 0; cb < 2; ++cb) {
          int lc = (cw * 2 + cb) * 16 + r16;
#pragma unroll
          for (int j = 0; j < 4; ++j) {
            int rr = q * 4 + j;
            float v = a3[cb][j] + part3[0][cw][cb][rr][r16] + part3[1][cw][cb][rr][r16] +
                      part3[2][cw][cb][rr][r16] + bov[cb];
            pub[rr * 128 + lc] = f2bf(fmaxf(v, 0.f));
          }
        }
      }
      __syncthreads();
      // publish h_new slice (u32 agent-scope stores -> LLC)
      {
        int rr = tid >> 6, c2 = tid & 63;
        unsigned word = ((const unsigned*)pub)[rr * 64 + c2];
        __hip_atomic_store(&hnewG[g * 4096 + rr * 256 + m * 64 + c2], word,
                           __ATOMIC_RELAXED, __HIP_MEMORY_SCOPE_AGENT);
      }
      __syncthreads();                    // all waves' publish stores drained
      if (tid == 0) {
        asm volatile("s_waitcnt vmcnt(0)" ::: "memory");
        __hip_atomic_store(&flags[g * 16 + m], (unsigned)(t + 1),
                           __ATOMIC_RELEASE, __HIP_MEMORY_SCOPE_AGENT);
      }
    }
  }
}

// ---------------------------------------------------------------------------
// Logits GEMM (unchanged, proven): out[b][t][v] = cat[t*64+b] @ WbT[v] + bout
// ---------------------------------------------------------------------------
__global__ __launch_bounds__(256) void logits_gemm(const short* __restrict__ cat,
                                                   const short* __restrict__ WbT,
                                                   const float* __restrict__ bout,
                                                   float* __restrict__ out) {
  const int mbase = (blockIdx.x >> 3) * 128;
  const int vbase = (blockIdx.x & 7) * 128;
  __shared__ short sA[128 * 32];
  __shared__ short sB[128 * 32];
  const int tid = threadIdx.x, l = tid & 63, w = tid >> 6;
  const int wm = w & 1, wn = w >> 1;

  f32x4 acc[4][4];
#pragma unroll
  for (int i = 0; i < 4; ++i)
#pragma unroll
    for (int j = 0; j < 4; ++j) acc[i][j] = (f32x4){0.f, 0.f, 0.f, 0.f};

  for (int kb = 0; kb < 1024; kb += 32) {
    __syncthreads();
#pragma unroll
    for (int it = 0; it < 2; ++it) {
      int c = tid + 256 * it;
      int ml = c >> 2, kss = c & 3;
      *(short8*)&sA[ml * 32 + kss * 8] = *(const short8*)&cat[(mbase + ml) * 1024 + kb + kss * 8];
      *(short8*)&sB[ml * 32 + kss * 8] = *(const short8*)&WbT[(vbase + ml) * 1024 + kb + kss * 8];
    }
    __syncthreads();
    short8 af[4], bf[4];
#pragma unroll
    for (int fr = 0; fr < 4; ++fr)
      af[fr] = *(const short8*)&sA[(wm * 64 + fr * 16 + (l & 15)) * 32 + (l >> 4) * 8];
#pragma unroll
    for (int fc = 0; fc < 4; ++fc)
      bf[fc] = *(const short8*)&sB[(wn * 64 + fc * 16 + (l & 15)) * 32 + (l >> 4) * 8];
#pragma unroll
    for (int fr = 0; fr < 4; ++fr)
#pragma unroll
      for (int fc = 0; fc < 4; ++fc) acc[fr][fc] = MFMA16(af[fr], bf[fc], acc[fr][fc]);
  }

  float bb[4];
#pragma unroll
  for (int fc = 0; fc < 4; ++fc) bb[fc] = bout[512 + vbase + wn * 64 + fc * 16 + (l & 15)];

#pragma unroll
  for (int fr = 0; fr < 4; ++fr) {
#pragma unroll
    for (int fc = 0; fc < 4; ++fc) {
      int v = vbase + wn * 64 + fc * 16 + (l & 15);
#pragma unroll
      for (int j = 0; j < 4; ++j) {
        int mm = mbase + wm * 64 + fr * 16 + (l >> 4) * 4 + j;
        int b = mm & 63, tt = mm >> 6;
        out[((long)(b * T_ + tt)) * 1024 + v] = acc[fr][fc][j] + bb[fc];
      }
    }
  }
}

extern "C" void kernel_launch(void* const* d_in, const int* in_sizes, int n_in,
                              void* d_out, int out_size, void* d_ws, size_t ws_size,
                              hipStream_t stream) {
  const int*   x    = (const int*)d_in[0];
  const float* emb  = (const float*)d_in[1];
  const float* W0   = (const float*)d_in[2];
  const float* b0   = (const float*)d_in[3];
  const float* W1   = (const float*)d_in[4];
  const float* b1   = (const float*)d_in[5];
  const float* Wout = (const float*)d_in[6];
  const float* bout = (const float*)d_in[7];
  float* out = (float*)d_out;

  char* ws = (char*)d_ws;
  unsigned* flags = (unsigned*)(ws + FLG_OFF);
  unsigned* hnewG = (unsigned*)(ws + HNEW_OFF);
  short* cat  = (short*)(ws + CAT_OFF);
  short* W0f  = (short*)(ws + W0F_OFF);
  short* W1f  = (short*)(ws + W1F_OFF);
  short* Waf  = (short*)(ws + WAF_OFF);
  short* WbT  = (short*)(ws + WBT_OFF);
  float* Epr  = (float*)(ws + EPR_OFF);

  // zero flags + h_init
  hipMemsetAsync(ws, 0, CAT_OFF, stream);
  pack_weights<<<1024, 256, 0, stream>>>(W0, W1, Wout, W0f, W1f, Waf, WbT);
  eprime<<<64, 256, 0, stream>>>(emb, W0, Epr);
  rnn_recur<<<16, 1024, 0, stream>>>(x, b0, b1, bout, W0f, W1f, Waf, Epr, cat, hnewG, flags);
  logits_gemm<<<2048, 256, 0, stream>>>(cat, WbT, bout, out);
}

// Round 9
// 19251.146 us; speedup vs baseline: 1.1211x; 1.1211x over previous
//
#include <hip/hip_runtime.h>
#include <hip/hip_bf16.h>

typedef __attribute__((ext_vector_type(8))) short short8;
typedef __attribute__((ext_vector_type(4))) float f32x4;

#define MFMA16(a, b, c) __builtin_amdgcn_mfma_f32_16x16x32_bf16((a), (b), (c), 0, 0, 0)

#define B_ 64
#define T_ 512

// ws layout (bytes)
#define FLG_OFF  0u          // 8 groups * 16 u32 = 512B
#define HNEW_OFF 1024u       // 2 bufs * 8 groups * 8 rows * 512 * 2B = 131072
#define CAT_OFF  132096u     // 512*64*1024*2 = 67108864
#define W0F_OFF  67240960u   // 524288   (W0h blob, K=512)
#define W1F_OFF  67765248u   // 524288   (W1 blob, K=512)
#define WAF_OFF  68289536u   // 1048576  (Wout[:, :512] blob, K=1024)
#define WBT_OFF  69338112u   // 2097152  (Wout[:, 512:] transposed)
#define EPR_OFF  71435264u   // 1024*512*4 = 2097152 (E' = emb @ W0[:512,:], fp32)
// end: 73532416

__device__ __forceinline__ short f2bf(float f) {
  unsigned u = __float_as_uint(f);
  unsigned r = (u + 0x7fffu + ((u >> 16) & 1u)) >> 16;
  return (short)r;
}

// ---------------------------------------------------------------------------
// Weight packing (proven): bf16 MFMA B-fragment blobs.
// Blob for (K,N): idx = ((cb*(K/32) + s)*64 + l)*8 + j
//   holds W[s*32 + (l>>4)*8 + j][cb*16 + (l&15)]
// ---------------------------------------------------------------------------
__global__ void pack_weights(const float* __restrict__ W0, const float* __restrict__ W1,
                             const float* __restrict__ Wout,
                             short* __restrict__ W0f, short* __restrict__ W1f,
                             short* __restrict__ Waf, short* __restrict__ WbT) {
  const int total = 262144 + 262144 + 524288 + 1048576;
  for (int i = blockIdx.x * blockDim.x + threadIdx.x; i < total; i += gridDim.x * blockDim.x) {
    if (i < 262144) {                       // W0h: K=512, N=512
      int j = i & 7, l = (i >> 3) & 63, rest = i >> 9;
      int s = rest & 15, cb = rest >> 4;
      int k = s * 32 + ((l >> 4) << 3) + j, n = (cb << 4) + (l & 15);
      W0f[i] = f2bf(W0[(512 + k) * 512 + n]);
    } else if (i < 524288) {                // W1: K=512, N=512
      int ii = i - 262144;
      int j = ii & 7, l = (ii >> 3) & 63, rest = ii >> 9;
      int s = rest & 15, cb = rest >> 4;
      int k = s * 32 + ((l >> 4) << 3) + j, n = (cb << 4) + (l & 15);
      W1f[ii] = f2bf(W1[k * 512 + n]);
    } else if (i < 1048576) {               // Wa: Wout[:, :512], K=1024
      int ii = i - 524288;
      int j = ii & 7, l = (ii >> 3) & 63, rest = ii >> 9;
      int s = rest & 31, cb = rest >> 5;
      int k = s * 32 + ((l >> 4) << 3) + j, n = (cb << 4) + (l & 15);
      Waf[ii] = f2bf(Wout[k * 1536 + n]);
    } else {                                // WbT
      int ii = i - 1048576;
      int v = ii >> 10, kk = ii & 1023;
      WbT[ii] = f2bf(Wout[kk * 1536 + 512 + v]);
    }
  }
}

// ---------------------------------------------------------------------------
// E'[v][n] = sum_k emb[v][k] * W0[k][n]  (fp32 exact) — proven R7/R8.
// ---------------------------------------------------------------------------
__global__ __launch_bounds__(256) void eprime(const float* __restrict__ emb,
                                              const float* __restrict__ W0,
                                              float* __restrict__ Epr) {
  __shared__ float eL[16][512];
  const int v0 = blockIdx.x * 16, tid = threadIdx.x;
  for (int i = tid; i < 16 * 512; i += 256)
    eL[i >> 9][i & 511] = emb[(v0 + (i >> 9)) * 512 + (i & 511)];
  __syncthreads();
  float acc[32];
#pragma unroll
  for (int v = 0; v < 32; ++v) acc[v] = 0.f;
#pragma unroll 4
  for (int k = 0; k < 512; ++k) {
    float wa = W0[k * 512 + tid];
    float wb = W0[k * 512 + 256 + tid];
#pragma unroll
    for (int v = 0; v < 16; ++v) {
      float e = eL[v][k];
      acc[2 * v]     = fmaf(e, wa, acc[2 * v]);
      acc[2 * v + 1] = fmaf(e, wb, acc[2 * v + 1]);
    }
  }
#pragma unroll
  for (int v = 0; v < 16; ++v) {
    Epr[(v0 + v) * 512 + tid]       = acc[2 * v];
    Epr[(v0 + v) * 512 + 256 + tid] = acc[2 * v + 1];
  }
}

// ---------------------------------------------------------------------------
// Recurrence: 64 blocks x 1024 threads (16 waves). Group g = bid>>3 owns
// batch rows [8g, 8g+8); member m = bid&7. Every member computes h0 and h1
// FULLY (redundantly; W0h + W1 register-resident, full-K per wave), h_new
// only for its 64-col slice (Wa split 8 ways, K-split 4x across waves).
// ONE inter-block barrier per step. hnewG is DOUBLE-BUFFERED (t&1): a member
// publishing h_new(t) writes buffer (t+1)&1 while laggards stage buffer t&1
// — race-free under the per-step flag barrier (fixes R8's absmax failure).
// ---------------------------------------------------------------------------
__global__ __launch_bounds__(1024, 4) void rnn_recur(
    const int* __restrict__ x,
    const float* __restrict__ b0, const float* __restrict__ b1, const float* __restrict__ bout,
    const short* __restrict__ W0f, const short* __restrict__ W1f, const short* __restrict__ Waf,
    const float* __restrict__ Epr,
    short* __restrict__ cat, unsigned* __restrict__ hnewG, unsigned* __restrict__ flags) {
  const int g = blockIdx.x >> 3, m = blockIdx.x & 7;
  const int tid = threadIdx.x, l = tid & 63, w = tid >> 6;
  const int q = l >> 4, r16 = l & 15, lrow = l & 7;
  const int kq = w >> 2, cw = w & 3;       // phase-3 roles: K-quarter, 16-col slice

  __shared__ short hst[8 * 512];           // h stage (swizzled, 8KB)
  __shared__ short h0s[8 * 512];
  __shared__ short h1s[8 * 512];
  __shared__ float part3[3][4][8][17];     // phase-3 partials [kq][cw][row][col+pad]
  __shared__ short pub[8 * 64];            // h_new slice staging
  __shared__ int x_lds[8][512];

  // ---- token ids into LDS
  for (int i = tid; i < 8 * 512; i += 1024)
    x_lds[i >> 9][i & 511] = x[(g * 8 + (i >> 9)) * T_ + (i & 511)];

  // ---- register-resident weights: wave w owns cols [32w, 32w+32) of h0/h1
  short8 w0r[2][16], w1r[2][16], war[8];
#pragma unroll
  for (int cb = 0; cb < 2; ++cb) {
    int cbg = w * 2 + cb;
#pragma unroll
    for (int s = 0; s < 16; ++s) {
      w0r[cb][s] = *(const short8*)&W0f[((cbg * 16 + s) * 64 + l) * 8];
      w1r[cb][s] = *(const short8*)&W1f[((cbg * 16 + s) * 64 + l) * 8];
    }
  }
  {
    int cbg3 = m * 4 + cw;                 // h_new col-block (member slice)
#pragma unroll
    for (int si = 0; si < 8; ++si)
      war[si] = *(const short8*)&Waf[((cbg3 * 32 + kq * 8 + si) * 64 + l) * 8];
  }

  const float b0v0 = b0[(w * 2) * 16 + r16],     b0v1 = b0[(w * 2 + 1) * 16 + r16];
  const float b1v0 = b1[(w * 2) * 16 + r16],     b1v1 = b1[(w * 2 + 1) * 16 + r16];
  const float bov  = bout[m * 64 + cw * 16 + r16];

  __syncthreads();                         // x_lds ready

  // ---- E' prefetch for t=0 (valid output rows are q<2 lanes)
  float epf[8];
#pragma unroll
  for (int i = 0; i < 8; ++i) epf[i] = 0.f;
  if (q < 2) {
#pragma unroll
    for (int j = 0; j < 4; ++j) {
      int xi = x_lds[q * 4 + j][0];
      epf[j]     = Epr[xi * 512 + (w * 2) * 16 + r16];
      epf[4 + j] = Epr[xi * 512 + (w * 2 + 1) * 16 + r16];
    }
  }

  for (int t = 0; t < T_; ++t) {
    // ===== barrier: h_new(t-1) published by all 8 members =====
    if (tid < 8) {
      int spins = 0;
      while (__hip_atomic_load(&flags[g * 16 + tid], __ATOMIC_RELAXED,
                               __HIP_MEMORY_SCOPE_AGENT) < (unsigned)t) {
        if (++spins > (1 << 22)) break;   // stopgap: degrade, don't hang
      }
    }
    __syncthreads();
    // ===== stage h (8KB) -> swizzled LDS (agent-scope 8B loads, buffer t&1) =====
    {
      unsigned long long hv = __hip_atomic_load(
          (const unsigned long long*)hnewG + (unsigned)(t & 1) * 8192 + g * 1024 + tid,
          __ATOMIC_RELAXED, __HIP_MEMORY_SCOPE_AGENT);
      int row = tid >> 7;
      int sidx = ((tid & 127) << 2) ^ (row << 3);   // short idx ^= row*8 (byte<<4)
      *(unsigned long long*)&hst[(row << 9) + sidx] = hv;
    }
    __syncthreads();

    // ===== phase 1: h0 = relu(E'[x_t] + h @ W0h + b0), full K per wave =====
    {
      f32x4 a0 = {0.f, 0.f, 0.f, 0.f}, a1 = {0.f, 0.f, 0.f, 0.f};
#pragma unroll
      for (int s = 0; s < 16; ++s) {
        short8 af = *(const short8*)&hst[(lrow << 9) + (((s << 5) + (q << 3)) ^ (lrow << 3))];
        a0 = MFMA16(af, w0r[0][s], a0);
        a1 = MFMA16(af, w0r[1][s], a1);
      }
      if (q < 2) {
#pragma unroll
        for (int j = 0; j < 4; ++j) {
          int rr = q * 4 + j;
          int c0 = (w * 2) * 16 + r16, c1 = (w * 2 + 1) * 16 + r16;
          short bf0 = f2bf(fmaxf(a0[j] + epf[j] + b0v0, 0.f));
          short bf1 = f2bf(fmaxf(a1[j] + epf[4 + j] + b0v1, 0.f));
          h0s[(rr << 9) + (c0 ^ (rr << 3))] = bf0;
          h0s[(rr << 9) + (c1 ^ (rr << 3))] = bf1;
          if (m == 0) {
            cat[(t * B_ + g * 8 + rr) * 1024 + c0] = bf0;
            cat[(t * B_ + g * 8 + rr) * 1024 + c1] = bf1;
          }
        }
      }
    }
    __syncthreads();

    // ===== phase 2: h1 = relu(h0 @ W1 + b1), full K per wave =====
    {
      f32x4 a0 = {0.f, 0.f, 0.f, 0.f}, a1 = {0.f, 0.f, 0.f, 0.f};
#pragma unroll
      for (int s = 0; s < 16; ++s) {
        short8 af = *(const short8*)&h0s[(lrow << 9) + (((s << 5) + (q << 3)) ^ (lrow << 3))];
        a0 = MFMA16(af, w1r[0][s], a0);
        a1 = MFMA16(af, w1r[1][s], a1);
      }
      if (q < 2) {
#pragma unroll
        for (int j = 0; j < 4; ++j) {
          int rr = q * 4 + j;
          int c0 = (w * 2) * 16 + r16, c1 = (w * 2 + 1) * 16 + r16;
          short bf0 = f2bf(fmaxf(a0[j] + b1v0, 0.f));
          short bf1 = f2bf(fmaxf(a1[j] + b1v1, 0.f));
          h1s[(rr << 9) + (c0 ^ (rr << 3))] = bf0;
          h1s[(rr << 9) + (c1 ^ (rr << 3))] = bf1;
          if (m == 1) {
            cat[(t * B_ + g * 8 + rr) * 1024 + 512 + c0] = bf0;
            cat[(t * B_ + g * 8 + rr) * 1024 + 512 + c1] = bf1;
          }
        }
        // E' prefetch for t+1 (overlaps phase 3)
        if (t + 1 < T_) {
#pragma unroll
          for (int j = 0; j < 4; ++j) {
            int xi = x_lds[q * 4 + j][t + 1];
            epf[j]     = Epr[xi * 512 + (w * 2) * 16 + r16];
            epf[4 + j] = Epr[xi * 512 + (w * 2 + 1) * 16 + r16];
          }
        }
      }
    }
    if (t == T_ - 1) break;               // last h_new unused; cat complete
    __syncthreads();

    // ===== phase 3: h_new slice = relu([h0,h1] @ Wa[:, m-slice] + bout) =====
    {
      f32x4 a3 = {0.f, 0.f, 0.f, 0.f};
      const short* src = (kq < 2) ? h0s : h1s;
      int kb = (kq & 1) << 8;             // 256-element half
#pragma unroll
      for (int si = 0; si < 8; ++si) {
        short8 af = *(const short8*)&src[(lrow << 9) +
                     (((kb + si * 32 + q * 8)) ^ (lrow << 3))];
        a3 = MFMA16(af, war[si], a3);
      }
      if (kq < 3 && q < 2) {
#pragma unroll
        for (int j = 0; j < 4; ++j) part3[kq][cw][q * 4 + j][r16] = a3[j];
      }
      __syncthreads();
      if (kq == 3 && q < 2) {
#pragma unroll
        for (int j = 0; j < 4; ++j) {
          int rr = q * 4 + j;
          float v = a3[j] + part3[0][cw][rr][r16] + part3[1][cw][rr][r16] +
                    part3[2][cw][rr][r16] + bov;
          pub[rr * 64 + cw * 16 + r16] = f2bf(fmaxf(v, 0.f));
        }
      }
      __syncthreads();
      // publish h_new slice into buffer (t+1)&1 (agent-scope u32 stores)
      if (tid < 256) {
        unsigned word = ((const unsigned*)pub)[tid];
        __hip_atomic_store(&hnewG[(unsigned)((t + 1) & 1) * 16384 + g * 2048 +
                                  (tid >> 5) * 256 + m * 32 + (tid & 31)],
                           word, __ATOMIC_RELAXED, __HIP_MEMORY_SCOPE_AGENT);
      }
      __syncthreads();                    // all waves' publish stores drained
      if (tid == 0)
        __hip_atomic_store(&flags[g * 16 + m], (unsigned)(t + 1),
                           __ATOMIC_RELEASE, __HIP_MEMORY_SCOPE_AGENT);
    }
  }
}

// ---------------------------------------------------------------------------
// Logits GEMM (proven): out[b][t][v] = cat[t*64+b] @ WbT[v] + bout[512+v]
// ---------------------------------------------------------------------------
__global__ __launch_bounds__(256) void logits_gemm(const short* __restrict__ cat,
                                                   const short* __restrict__ WbT,
                                                   const float* __restrict__ bout,
                                                   float* __restrict__ out) {
  const int mbase = (blockIdx.x >> 3) * 128;
  const int vbase = (blockIdx.x & 7) * 128;
  __shared__ short sA[128 * 32];
  __shared__ short sB[128 * 32];
  const int tid = threadIdx.x, l = tid & 63, w = tid >> 6;
  const int wm = w & 1, wn = w >> 1;

  f32x4 acc[4][4];
#pragma unroll
  for (int i = 0; i < 4; ++i)
#pragma unroll
    for (int j = 0; j < 4; ++j) acc[i][j] = (f32x4){0.f, 0.f, 0.f, 0.f};

  for (int kb = 0; kb < 1024; kb += 32) {
    __syncthreads();
#pragma unroll
    for (int it = 0; it < 2; ++it) {
      int c = tid + 256 * it;
      int ml = c >> 2, kss = c & 3;
      *(short8*)&sA[ml * 32 + kss * 8] = *(const short8*)&cat[(mbase + ml) * 1024 + kb + kss * 8];
      *(short8*)&sB[ml * 32 + kss * 8] = *(const short8*)&WbT[(vbase + ml) * 1024 + kb + kss * 8];
    }
    __syncthreads();
    short8 af[4], bf[4];
#pragma unroll
    for (int fr = 0; fr < 4; ++fr)
      af[fr] = *(const short8*)&sA[(wm * 64 + fr * 16 + (l & 15)) * 32 + (l >> 4) * 8];
#pragma unroll
    for (int fc = 0; fc < 4; ++fc)
      bf[fc] = *(const short8*)&sB[(wn * 64 + fc * 16 + (l & 15)) * 32 + (l >> 4) * 8];
#pragma unroll
    for (int fr = 0; fr < 4; ++fr)
#pragma unroll
      for (int fc = 0; fc < 4; ++fc) acc[fr][fc] = MFMA16(af[fr], bf[fc], acc[fr][fc]);
  }

  float bb[4];
#pragma unroll
  for (int fc = 0; fc < 4; ++fc) bb[fc] = bout[512 + vbase + wn * 64 + fc * 16 + (l & 15)];

#pragma unroll
  for (int fr = 0; fr < 4; ++fr) {
#pragma unroll
    for (int fc = 0; fc < 4; ++fc) {
      int v = vbase + wn * 64 + fc * 16 + (l & 15);
#pragma unroll
      for (int j = 0; j < 4; ++j) {
        int mm = mbase + wm * 64 + fr * 16 + (l >> 4) * 4 + j;
        int b = mm & 63, tt = mm >> 6;
        out[((long)(b * T_ + tt)) * 1024 + v] = acc[fr][fc][j] + bb[fc];
      }
    }
  }
}

extern "C" void kernel_launch(void* const* d_in, const int* in_sizes, int n_in,
                              void* d_out, int out_size, void* d_ws, size_t ws_size,
                              hipStream_t stream) {
  const int*   x    = (const int*)d_in[0];
  const float* emb  = (const float*)d_in[1];
  const float* W0   = (const float*)d_in[2];
  const float* b0   = (const float*)d_in[3];
  const float* W1   = (const float*)d_in[4];
  const float* b1   = (const float*)d_in[5];
  const float* Wout = (const float*)d_in[6];
  const float* bout = (const float*)d_in[7];
  float* out = (float*)d_out;

  char* ws = (char*)d_ws;
  unsigned* flags = (unsigned*)(ws + FLG_OFF);
  unsigned* hnewG = (unsigned*)(ws + HNEW_OFF);
  short* cat  = (short*)(ws + CAT_OFF);
  short* W0f  = (short*)(ws + W0F_OFF);
  short* W1f  = (short*)(ws + W1F_OFF);
  short* Waf  = (short*)(ws + WAF_OFF);
  short* WbT  = (short*)(ws + WBT_OFF);
  float* Epr  = (float*)(ws + EPR_OFF);

  // zero flags + both h buffers (h_init = 0)
  hipMemsetAsync(ws, 0, CAT_OFF, stream);
  pack_weights<<<1024, 256, 0, stream>>>(W0, W1, Wout, W0f, W1f, Waf, WbT);
  eprime<<<64, 256, 0, stream>>>(emb, W0, Epr);
  rnn_recur<<<64, 1024, 0, stream>>>(x, b0, b1, bout, W0f, W1f, Waf, Epr, cat, hnewG, flags);
  logits_gemm<<<2048, 256, 0, stream>>>(cat, WbT, bout, out);
}

// Round 11
// 13529.819 us; speedup vs baseline: 1.5952x; 1.4229x over previous
//
#include <hip/hip_runtime.h>
#include <hip/hip_bf16.h>

typedef __attribute__((ext_vector_type(8))) short short8;
typedef __attribute__((ext_vector_type(4))) float f32x4;
typedef __attribute__((ext_vector_type(2))) unsigned long long u64x2;

#define MFMA16(a, b, c) __builtin_amdgcn_mfma_f32_16x16x32_bf16((a), (b), (c), 0, 0, 0)

#define B_ 64
#define T_ 512

// ws layout (bytes)
#define FLG_OFF 0u            // 8 groups * 64 u32 (32 used) = 2048
#define HDB_OFF 2048u         // 2 * 64 * 512 * 2B = 131072 (h double buffer)
#define CAT_OFF 133120u       // 512*64*1024*2 = 67108864
#define W0F_OFF 67241984u     // 524288  (W0h blob, K=512)
#define W1F_OFF 67766272u     // 524288  (W1 blob, K=512)
#define WAF_OFF 68290560u     // 1048576 (Wout[:, :512] blob, K=1024)
#define WBT_OFF 69339136u     // 2097152 (Wout[:, 512:] transposed)
#define EPR_OFF 71436288u     // 1024*512*4 = 2097152 (E' = emb @ W0[:512,:], fp32)
// end: 73533440

__device__ __forceinline__ short f2bf(float f) {
  unsigned u = __float_as_uint(f);
  unsigned r = (u + 0x7fffu + ((u >> 16) & 1u)) >> 16;
  return (short)r;
}

// agent-scope coherent 16B load (LLC; proven R1-R9)
__device__ __forceinline__ short8 ld8(const short* p) {
  union { u64x2 q; short8 s; } u;
  u.q.x = __hip_atomic_load((const unsigned long long*)p, __ATOMIC_RELAXED, __HIP_MEMORY_SCOPE_AGENT);
  u.q.y = __hip_atomic_load(((const unsigned long long*)p) + 1, __ATOMIC_RELAXED, __HIP_MEMORY_SCOPE_AGENT);
  return u.s;
}

// ---------------------------------------------------------------------------
// Weight packing (proven): bf16 MFMA B-fragment blobs.
// Blob for (K,N): idx = ((cb*(K/32) + s)*64 + l)*8 + j
//   holds W[s*32 + (l>>4)*8 + j][cb*16 + (l&15)]
// ---------------------------------------------------------------------------
__global__ void pack_weights(const float* __restrict__ W0, const float* __restrict__ W1,
                             const float* __restrict__ Wout,
                             short* __restrict__ W0f, short* __restrict__ W1f,
                             short* __restrict__ Waf, short* __restrict__ WbT) {
  const int total = 262144 + 262144 + 524288 + 1048576;
  for (int i = blockIdx.x * blockDim.x + threadIdx.x; i < total; i += gridDim.x * blockDim.x) {
    if (i < 262144) {                       // W0h: K=512, N=512
      int j = i & 7, l = (i >> 3) & 63, rest = i >> 9;
      int s = rest & 15, cb = rest >> 4;
      int k = s * 32 + ((l >> 4) << 3) + j, n = (cb << 4) + (l & 15);
      W0f[i] = f2bf(W0[(512 + k) * 512 + n]);
    } else if (i < 524288) {                // W1: K=512, N=512
      int ii = i - 262144;
      int j = ii & 7, l = (ii >> 3) & 63, rest = ii >> 9;
      int s = rest & 15, cb = rest >> 4;
      int k = s * 32 + ((l >> 4) << 3) + j, n = (cb << 4) + (l & 15);
      W1f[ii] = f2bf(W1[k * 512 + n]);
    } else if (i < 1048576) {               // Wa: Wout[:, :512], K=1024
      int ii = i - 524288;
      int j = ii & 7, l = (ii >> 3) & 63, rest = ii >> 9;
      int s = rest & 31, cb = rest >> 5;
      int k = s * 32 + ((l >> 4) << 3) + j, n = (cb << 4) + (l & 15);
      Waf[ii] = f2bf(Wout[k * 1536 + n]);
    } else {                                // WbT
      int ii = i - 1048576;
      int v = ii >> 10, kk = ii & 1023;
      WbT[ii] = f2bf(Wout[kk * 1536 + 512 + v]);
    }
  }
}

// ---------------------------------------------------------------------------
// E'[v][n] = sum_k emb[v][k] * W0[k][n]  (fp32 exact) — proven R7+.
// ---------------------------------------------------------------------------
__global__ __launch_bounds__(256) void eprime(const float* __restrict__ emb,
                                              const float* __restrict__ W0,
                                              float* __restrict__ Epr) {
  __shared__ float eL[16][512];
  const int v0 = blockIdx.x * 16, tid = threadIdx.x;
  for (int i = tid; i < 16 * 512; i += 256)
    eL[i >> 9][i & 511] = emb[(v0 + (i >> 9)) * 512 + (i & 511)];
  __syncthreads();
  float acc[32];
#pragma unroll
  for (int v = 0; v < 32; ++v) acc[v] = 0.f;
#pragma unroll 4
  for (int k = 0; k < 512; ++k) {
    float wa = W0[k * 512 + tid];
    float wb = W0[k * 512 + 256 + tid];
#pragma unroll
    for (int v = 0; v < 16; ++v) {
      float e = eL[v][k];
      acc[2 * v]     = fmaf(e, wa, acc[2 * v]);
      acc[2 * v + 1] = fmaf(e, wb, acc[2 * v + 1]);
    }
  }
#pragma unroll
  for (int v = 0; v < 16; ++v) {
    Epr[(v0 + v) * 512 + tid]       = acc[2 * v];
    Epr[(v0 + v) * 512 + 256 + tid] = acc[2 * v + 1];
  }
}

// ---------------------------------------------------------------------------
// Wave-granular barrier on 32 wave-flags per group (R2-proven agent atomics).
// ---------------------------------------------------------------------------
__device__ __forceinline__ void wave_wait32(const unsigned* gf, unsigned tag) {
  const int lane = threadIdx.x & 63;
  unsigned v = 0xFFFFFFFFu;
  int spins = 0;
  do {
    if (lane < 32)
      v = __hip_atomic_load(gf + lane, __ATOMIC_RELAXED, __HIP_MEMORY_SCOPE_AGENT);
  } while (__ballot((int)(v >= tag)) != ~0ull && ++spins < (1 << 16));
  __builtin_amdgcn_sched_barrier(0);
  asm volatile("" ::: "memory");
}

__device__ __forceinline__ void wave_signal(unsigned* myflag, unsigned tag) {
  asm volatile("s_waitcnt vmcnt(0)" ::: "memory");   // this wave's stores are at LLC
  if ((threadIdx.x & 63) == 0)
    __hip_atomic_store(myflag, tag, __ATOMIC_RELAXED, __HIP_MEMORY_SCOPE_AGENT);
}

// ---------------------------------------------------------------------------
// Fused persistent kernel: 256 blocks x 256 threads.
// Blocks 0..63: recurrence. Group g = bid>>3 owns rows [8g,8g+8); member
// m = bid&7 owns cols [64m,64m+64); wave w owns 16 cols with FULL K in
// registers (4 x 16 short8 = 256 VGPR). No __syncthreads in the hot loop:
// wave-granular flags. Per phase: wait -> 16 LLC A-loads -> 16-32 MFMA ->
// in-wave LDS transpose -> 32 x 8B coherent publish (FULL 256B tile — R10's
// bug was publishing only 128B) -> signal.
// Blocks 64..255: logits consumers — poll flags, then 128x128 GEMM tiles.
// ---------------------------------------------------------------------------
__global__ __launch_bounds__(256, 1) void rnn_fused(
    const int* __restrict__ x,
    const float* __restrict__ b0, const float* __restrict__ b1, const float* __restrict__ bout,
    const short* __restrict__ W0f, const short* __restrict__ W1f, const short* __restrict__ Waf,
    const short* __restrict__ WbT, const float* __restrict__ Epr,
    short* __restrict__ cat, short* __restrict__ hdb,
    unsigned* __restrict__ flags, float* __restrict__ out) {
  const int bid = blockIdx.x;
  const int tid = threadIdx.x, l = tid & 63, w = tid >> 6;

  if (bid < 64) {
    // =================== recurrence path ===================
    const int g = bid >> 3, m = bid & 7;
    const int q = l >> 4, r16 = l & 15, lrow = l & 7;
    const int cb = m * 4 + w;              // global 16-col block
    const int cbase = cb * 16;
    const int col = cbase + r16;
    const int prow = l >> 2, pq4 = (l & 3) * 4;   // publish coords (32 lanes)

    __shared__ int x_lds[8][512];
    __shared__ short scr[4][128];
    short* scrw = scr[w];

    for (int i = tid; i < 8 * 512; i += 256)
      x_lds[i >> 9][i & 511] = x[(g * 8 + (i >> 9)) * T_ + (i & 511)];

    short8 w0r[16], w1r[16], waL[16], waH[16];
#pragma unroll
    for (int s = 0; s < 16; ++s) {
      w0r[s] = *(const short8*)&W0f[((cb * 16 + s) * 64 + l) * 8];
      w1r[s] = *(const short8*)&W1f[((cb * 16 + s) * 64 + l) * 8];
      waL[s] = *(const short8*)&Waf[((cb * 32 + s) * 64 + l) * 8];
      waH[s] = *(const short8*)&Waf[((cb * 32 + 16 + s) * 64 + l) * 8];
    }
    const float b0v = b0[col], b1v = b1[col], bov = bout[col];
    unsigned* gflags = flags + g * 64;
    unsigned* myflag = gflags + m * 4 + w;
    __syncthreads();                       // x_lds ready (only block barrier)

    float epf[4] = {0.f, 0.f, 0.f, 0.f};
    if (q < 2) {
#pragma unroll
      for (int j = 0; j < 4; ++j) epf[j] = Epr[x_lds[q * 4 + j][0] * 512 + col];
    }

    for (int t = 0; t < T_; ++t) {
      // ===== P1: h0 = relu(E' + W0h^T h + b0) =====
      wave_wait32(gflags, (unsigned)(3 * t));
      {
        f32x4 acc = {0.f, 0.f, 0.f, 0.f};
        const short* hp = hdb + (t & 1) * 32768 + (g * 8 + lrow) * 512 + q * 8;
#pragma unroll
        for (int s = 0; s < 16; ++s) acc = MFMA16(ld8(hp + s * 32), w0r[s], acc);
        if (q < 2) {
#pragma unroll
          for (int j = 0; j < 4; ++j)
            scrw[(q * 4 + j) * 16 + r16] = f2bf(fmaxf(acc[j] + epf[j] + b0v, 0.f));
        }
        asm volatile("s_waitcnt lgkmcnt(0)" ::: "memory");
        __builtin_amdgcn_wave_barrier();
        if (l < 32) {
          unsigned long long vv = *(const unsigned long long*)&scrw[prow * 16 + pq4];
          __hip_atomic_store(
              (unsigned long long*)(cat + (t * B_ + g * 8 + prow) * 1024 + cbase + pq4),
              vv, __ATOMIC_RELAXED, __HIP_MEMORY_SCOPE_AGENT);
        }
        wave_signal(myflag, (unsigned)(3 * t + 1));
      }

      // ===== P2: h1 = relu(W1^T h0 + b1); partial = Wa_lo^T h0 =====
      wave_wait32(gflags, (unsigned)(3 * t + 1));
      f32x4 pacc = {0.f, 0.f, 0.f, 0.f};
      {
        f32x4 acc = {0.f, 0.f, 0.f, 0.f};
        const short* c0 = cat + (t * B_ + g * 8 + lrow) * 1024 + q * 8;
#pragma unroll
        for (int s = 0; s < 16; ++s) {
          short8 a = ld8(c0 + s * 32);
          acc = MFMA16(a, w1r[s], acc);
          pacc = MFMA16(a, waL[s], pacc);
        }
        if (q < 2) {
#pragma unroll
          for (int j = 0; j < 4; ++j)
            scrw[(q * 4 + j) * 16 + r16] = f2bf(fmaxf(acc[j] + b1v, 0.f));
        }
        asm volatile("s_waitcnt lgkmcnt(0)" ::: "memory");
        __builtin_amdgcn_wave_barrier();
        if (l < 32) {
          unsigned long long vv = *(const unsigned long long*)&scrw[prow * 16 + pq4];
          __hip_atomic_store(
              (unsigned long long*)(cat + (t * B_ + g * 8 + prow) * 1024 + 512 + cbase + pq4),
              vv, __ATOMIC_RELAXED, __HIP_MEMORY_SCOPE_AGENT);
        }
        wave_signal(myflag, (unsigned)(3 * t + 2));
      }
      // E' prefetch for t+1 (independent; overlaps P3 wait+compute)
      if (q < 2 && t + 1 < T_) {
#pragma unroll
        for (int j = 0; j < 4; ++j) epf[j] = Epr[x_lds[q * 4 + j][t + 1] * 512 + col];
      }
      if (t == T_ - 1) break;              // cat complete; last h_new unused

      // ===== P3: h_new = relu(partial + Wa_hi^T h1 + bout) =====
      wave_wait32(gflags, (unsigned)(3 * t + 2));
      {
        const short* c1 = cat + (t * B_ + g * 8 + lrow) * 1024 + 512 + q * 8;
#pragma unroll
        for (int s = 0; s < 16; ++s) pacc = MFMA16(ld8(c1 + s * 32), waH[s], pacc);
        if (q < 2) {
#pragma unroll
          for (int j = 0; j < 4; ++j)
            scrw[(q * 4 + j) * 16 + r16] = f2bf(fmaxf(pacc[j] + bov, 0.f));
        }
        asm volatile("s_waitcnt lgkmcnt(0)" ::: "memory");
        __builtin_amdgcn_wave_barrier();
        if (l < 32) {
          unsigned long long vv = *(const unsigned long long*)&scrw[prow * 16 + pq4];
          __hip_atomic_store(
              (unsigned long long*)(hdb + ((t + 1) & 1) * 32768 + (g * 8 + prow) * 512 + cbase + pq4),
              vv, __ATOMIC_RELAXED, __HIP_MEMORY_SCOPE_AGENT);
        }
        wave_signal(myflag, (unsigned)(3 * t + 3));
      }
    }
  } else {
    // =================== logits consumer path ===================
    __shared__ short sA[128 * 32];
    __shared__ short sB[128 * 32];
    const int wm = w & 1, wn = w >> 1;

    for (int tau = bid - 64; tau < 2048; tau += 192) {
      const int mb = tau >> 3, vb = tau & 7;
      const int mbase = mb * 128, vbase = vb * 128;
      const unsigned tag = (unsigned)(6 * mb + 5);   // P2 done for t = 2*mb+1

      // wait until all 8 groups' 32 wave-flags reach tag
      if (tid < 64) {
        unsigned mn;
        int spins = 0;
        do {
          mn = 0xFFFFFFFFu;
#pragma unroll
          for (int r = 0; r < 4; ++r) {
            int idx = r * 64 + tid;                  // 0..255
            unsigned v = __hip_atomic_load(flags + (idx >> 5) * 64 + (idx & 31),
                                           __ATOMIC_RELAXED, __HIP_MEMORY_SCOPE_AGENT);
            mn = mn < v ? mn : v;
          }
          if (__ballot((int)(mn >= tag)) == ~0ull) break;
          __builtin_amdgcn_s_sleep(2);
        } while (++spins < (1 << 16));
      }
      __syncthreads();
      asm volatile("" ::: "memory");

      f32x4 acc[4][4];
#pragma unroll
      for (int i = 0; i < 4; ++i)
#pragma unroll
        for (int j = 0; j < 4; ++j) acc[i][j] = (f32x4){0.f, 0.f, 0.f, 0.f};

      for (int kb = 0; kb < 1024; kb += 32) {
        __syncthreads();
#pragma unroll
        for (int it = 0; it < 2; ++it) {
          int c = tid + 256 * it;
          int ml = c >> 2, kss = c & 3;
          *(short8*)&sA[ml * 32 + kss * 8] = ld8(&cat[(mbase + ml) * 1024 + kb + kss * 8]);
          *(short8*)&sB[ml * 32 + kss * 8] = *(const short8*)&WbT[(vbase + ml) * 1024 + kb + kss * 8];
        }
        __syncthreads();
        short8 af[4], bf[4];
#pragma unroll
        for (int fr = 0; fr < 4; ++fr)
          af[fr] = *(const short8*)&sA[(wm * 64 + fr * 16 + (l & 15)) * 32 + (l >> 4) * 8];
#pragma unroll
        for (int fc = 0; fc < 4; ++fc)
          bf[fc] = *(const short8*)&sB[(wn * 64 + fc * 16 + (l & 15)) * 32 + (l >> 4) * 8];
#pragma unroll
        for (int fr = 0; fr < 4; ++fr)
#pragma unroll
          for (int fc = 0; fc < 4; ++fc) acc[fr][fc] = MFMA16(af[fr], bf[fc], acc[fr][fc]);
      }

      float bb[4];
#pragma unroll
      for (int fc = 0; fc < 4; ++fc) bb[fc] = bout[512 + vbase + wn * 64 + fc * 16 + (l & 15)];
#pragma unroll
      for (int fr = 0; fr < 4; ++fr) {
#pragma unroll
        for (int fc = 0; fc < 4; ++fc) {
          int v = vbase + wn * 64 + fc * 16 + (l & 15);
#pragma unroll
          for (int j = 0; j < 4; ++j) {
            int mm = mbase + wm * 64 + fr * 16 + (l >> 4) * 4 + j;
            int b = mm & 63, tt = mm >> 6;
            out[((long)(b * T_ + tt)) * 1024 + v] = acc[fr][fc][j] + bb[fc];
          }
        }
      }
      __syncthreads();
    }
  }
}

extern "C" void kernel_launch(void* const* d_in, const int* in_sizes, int n_in,
                              void* d_out, int out_size, void* d_ws, size_t ws_size,
                              hipStream_t stream) {
  const int*   x    = (const int*)d_in[0];
  const float* emb  = (const float*)d_in[1];
  const float* W0   = (const float*)d_in[2];
  const float* b0   = (const float*)d_in[3];
  const float* W1   = (const float*)d_in[4];
  const float* b1   = (const float*)d_in[5];
  const float* Wout = (const float*)d_in[6];
  const float* bout = (const float*)d_in[7];
  float* out = (float*)d_out;

  char* ws = (char*)d_ws;
  unsigned* flags = (unsigned*)(ws + FLG_OFF);
  short* hdb  = (short*)(ws + HDB_OFF);
  short* cat  = (short*)(ws + CAT_OFF);
  short* W0f  = (short*)(ws + W0F_OFF);
  short* W1f  = (short*)(ws + W1F_OFF);
  short* Waf  = (short*)(ws + WAF_OFF);
  short* WbT  = (short*)(ws + WBT_OFF);
  float* Epr  = (float*)(ws + EPR_OFF);

  // zero flags + h double buffer (h_init = 0)
  hipMemsetAsync(ws, 0, CAT_OFF, stream);
  pack_weights<<<1024, 256, 0, stream>>>(W0, W1, Wout, W0f, W1f, Waf, WbT);
  eprime<<<64, 256, 0, stream>>>(emb, W0, Epr);
  rnn_fused<<<256, 256, 0, stream>>>(x, b0, b1, bout, W0f, W1f, Waf, WbT, Epr,
                                     cat, hdb, flags, out);
}